// Round 5
// baseline (124.642 us; speedup 1.0000x reference)
//
#include <hip/hip_runtime.h>

#define NS 25
#define NQ 200
#define FG 16
#define FL 64
#define FTOT 80
#define D 512
#define WAY 5
#define MROWS 2000    // 25*80 support rows
#define MPAD 2080     // padded to 13 tiles of 160
#define NROWS 16000   // 200*80 query rows

typedef unsigned char u8;
typedef __attribute__((ext_vector_type(4))) float floatx4;
typedef __attribute__((ext_vector_type(4))) int intx4;
typedef __attribute__((ext_vector_type(8))) int intx8;

__device__ inline void gload_lds16(const void* g, void* l) {
    __builtin_amdgcn_global_load_lds(
        (const __attribute__((address_space(1))) unsigned int*)g,
        (__attribute__((address_space(3))) unsigned int*)l, 16, 0, 0);
}

// One wave per 512-elem row: L2-normalize, cast fp8 e4m3 (OCP), write concat
// layout. Block 4500: zero Sn pad rows + zero out[] + per-class 1/count.
__global__ void normalize_kernel(const float* __restrict__ sg, const float* __restrict__ sl,
                                 const float* __restrict__ qg, const float* __restrict__ ql,
                                 u8* __restrict__ Sn, u8* __restrict__ Qn,
                                 const int* __restrict__ labels,
                                 float* __restrict__ out, float* __restrict__ rcnt) {
    if (blockIdx.x == 4500) {
        intx4 z = {0, 0, 0, 0};
        intx4* pad = (intx4*)(Sn + (size_t)MROWS * D);   // 80 rows * 512 B = 2560 intx4
        for (int i = threadIdx.x; i < (MPAD - MROWS) * D / 16; i += 256) pad[i] = z;
        for (int i = threadIdx.x; i < NQ * WAY; i += 256) out[i] = 0.f;
        if (threadIdx.x == 0) {
            int counts[WAY] = {0, 0, 0, 0, 0};
            for (int s = 0; s < NS; ++s) counts[labels[s]]++;
            for (int c = 0; c < WAY; ++c) rcnt[c] = 1.0f / (float)(counts[c] ? counts[c] : 1);
        }
        return;
    }
    int wave = (blockIdx.x * blockDim.x + threadIdx.x) >> 6;
    int lane = threadIdx.x & 63;
    const int totalRows = MROWS + NROWS;   // 18000
    if (wave >= totalRows) return;

    const float* src;
    u8* dst;
    if (wave < MROWS) {
        int s = wave / FTOT, f = wave % FTOT;
        src = (f < FG) ? sg + (size_t)(s * FG + f) * D
                       : sl + (size_t)(s * FL + (f - FG)) * D;
        dst = Sn + (size_t)wave * D;
    } else {
        int r = wave - MROWS;
        int q = r / FTOT, f = r % FTOT;
        src = (f < FG) ? qg + (size_t)(q * FG + f) * D
                       : ql + (size_t)(q * FL + (f - FG)) * D;
        dst = Qn + (size_t)r * D;
    }

    // lane holds 8 contiguous elements [8*lane .. 8*lane+8)
    float4 v0 = ((const float4*)src)[2 * lane];
    float4 v1 = ((const float4*)src)[2 * lane + 1];
    float ss = v0.x*v0.x + v0.y*v0.y + v0.z*v0.z + v0.w*v0.w
             + v1.x*v1.x + v1.y*v1.y + v1.z*v1.z + v1.w*v1.w;
    #pragma unroll
    for (int off = 32; off > 0; off >>= 1) ss += __shfl_xor(ss, off, 64);
    float scale = 1.0f / fmaxf(sqrtf(ss), 1e-12f);

    int w0 = __builtin_amdgcn_cvt_pk_fp8_f32(v0.x * scale, v0.y * scale, 0, false);
    w0     = __builtin_amdgcn_cvt_pk_fp8_f32(v0.z * scale, v0.w * scale, w0, true);
    int w1 = __builtin_amdgcn_cvt_pk_fp8_f32(v1.x * scale, v1.y * scale, 0, false);
    w1     = __builtin_amdgcn_cvt_pk_fp8_f32(v1.z * scale, v1.w * scale, w1, true);
    ((int2*)dst)[lane] = make_int2(w0, w1);
}

// 160x160-tile fp8 NT GEMM, MX-scaled MFMA K=128 (scale=1.0), BK=128,
// XOR-swizzled LDS. 4 waves 2x2; each wave owns one 80x80 (s,q) block =
// 5x5 MFMA 16x16x128 tiles. Epilogue: sum (1-sim)^2 -> fused class-mean.
__global__ __launch_bounds__(256, 3) void gemm_kernel(const u8* __restrict__ Sn,
                                                      const u8* __restrict__ Qn,
                                                      const int* __restrict__ labels,
                                                      const float* __restrict__ rcnt,
                                                      float* __restrict__ out) {
    __shared__ u8 As[160][128];   // fp8, BK=128; 16B slot c holds global chunk c^((r>>1)&7)
    __shared__ u8 Bs[160][128];

    const int bx = blockIdx.x;          // 0..99  (query groups, 2 per block)
    const int by = blockIdx.y;          // 0..12  (support groups, 2 per block)
    const int tid = threadIdx.x;
    const int lane = tid & 63;
    const int w = tid >> 6;
    const int lm = lane & 15;
    const int lq = lane >> 4;           // 0..3: which 32-elem K-block of the frag
    const int wr = w >> 1;              // which 80-row half
    const int wc = w & 1;               // which 80-col half

    floatx4 acc[5][5];
    #pragma unroll
    for (int i = 0; i < 5; ++i)
        #pragma unroll
        for (int j = 0; j < 5; ++j) acc[i][j] = (floatx4){0.f, 0.f, 0.f, 0.f};

    const u8* Sbase = Sn + (size_t)by * 160 * D;
    const u8* Qbase = Qn + (size_t)bx * 160 * D;

    // staging: waves 0,1 -> A; waves 2,3 -> B. 20 slabs of 8 rows (1 KB each).
    const u8* gsrc = (w < 2) ? Sbase : Qbase;
    u8* ldst = (w < 2) ? (u8*)As : (u8*)Bs;
    const int sl0 = (w & 1) * 10;
    const int grow = lane >> 3;         // row within 8-row slab
    const int gc = lane & 7;            // 16B slot within 128B row

    #pragma unroll 1
    for (int kc = 0; kc < 4; ++kc) {
        const int k0 = kc * 128;
        __syncthreads();                // prev chunk's readers done
        #pragma unroll
        for (int t = 0; t < 10; ++t) {
            const int sl = sl0 + t;
            const int r = sl * 8 + grow;
            const int cp = gc ^ ((r >> 1) & 7);
            gload_lds16(gsrc + (size_t)r * D + k0 + cp * 16, ldst + sl * 1024);
        }
        __syncthreads();                // drains vmcnt (global_load_lds) too

        // A fragments: lane lq needs global 16B chunks 2lq, 2lq+1 of its row.
        intx8 a[5];
        #pragma unroll
        for (int i = 0; i < 5; ++i) {
            const int r = wr * 80 + i * 16 + lm;
            const int s = (r >> 1) & 7;
            const intx4 lo = *(const intx4*)&As[r][((2 * lq)     ^ s) * 16];
            const intx4 hi = *(const intx4*)&As[r][((2 * lq + 1) ^ s) * 16];
            a[i][0] = lo[0]; a[i][1] = lo[1]; a[i][2] = lo[2]; a[i][3] = lo[3];
            a[i][4] = hi[0]; a[i][5] = hi[1]; a[i][6] = hi[2]; a[i][7] = hi[3];
        }
        #pragma unroll
        for (int j = 0; j < 5; ++j) {
            const int r = wc * 80 + j * 16 + lm;
            const int s = (r >> 1) & 7;
            const intx4 lo = *(const intx4*)&Bs[r][((2 * lq)     ^ s) * 16];
            const intx4 hi = *(const intx4*)&Bs[r][((2 * lq + 1) ^ s) * 16];
            intx8 b;
            b[0] = lo[0]; b[1] = lo[1]; b[2] = lo[2]; b[3] = lo[3];
            b[4] = hi[0]; b[5] = hi[1]; b[6] = hi[2]; b[7] = hi[3];
            #pragma unroll
            for (int i = 0; i < 5; ++i)
                acc[i][j] = __builtin_amdgcn_mfma_scale_f32_16x16x128_f8f6f4(
                    a[i], b, acc[i][j],
                    0, 0,          // cbsz=fp8(e4m3), blgp=fp8(e4m3)
                    0, 0x7F,       // opsel_a, scale_a = e8m0(127) = 1.0
                    0, 0x7F);      // opsel_b, scale_b = 1.0
        }
    }

    // Epilogue: sum (1-sim)^2 over the wave's 80x80 block, fuse class-mean.
    float local = 0.f;
    #pragma unroll
    for (int i = 0; i < 5; ++i)
        #pragma unroll
        for (int j = 0; j < 5; ++j)
            #pragma unroll
            for (int r = 0; r < 4; ++r) {
                const float d = 1.0f - acc[i][j][r];
                local = fmaf(d, d, local);
            }
    #pragma unroll
    for (int off = 32; off > 0; off >>= 1) local += __shfl_down(local, off, 64);

    const int sIdx = by * 2 + wr;       // 25 = pad group, dropped
    const int qIdx = bx * 2 + wc;
    if (lane == 0 && sIdx < NS) {
        const int c = labels[sIdx];
        atomicAdd(&out[qIdx * WAY + c], -2.0f * local * rcnt[c]);
    }
}

extern "C" void kernel_launch(void* const* d_in, const int* in_sizes, int n_in,
                              void* d_out, int out_size, void* d_ws, size_t ws_size,
                              hipStream_t stream) {
    const float* sg = (const float*)d_in[0];
    const float* sl = (const float*)d_in[1];
    const int* labels = (const int*)d_in[2];
    const float* qg = (const float*)d_in[3];
    const float* ql = (const float*)d_in[4];
    float* out = (float*)d_out;

    u8* Sn = (u8*)d_ws;                          // 2080*512 fp8 (padded)
    u8* Qn = Sn + (size_t)MPAD * D;              // 16000*512 fp8
    float* rcnt = (float*)(Qn + (size_t)NROWS * D);

    normalize_kernel<<<4501, 256, 0, stream>>>(sg, sl, qg, ql, Sn, Qn, labels, out, rcnt);
    dim3 g2(100, 13);
    gemm_kernel<<<g2, 256, 0, stream>>>(Sn, Qn, labels, rcnt, out);
}

// Round 6
// 116.298 us; speedup vs baseline: 1.0717x; 1.0717x over previous
//
#include <hip/hip_runtime.h>

#define NS 25
#define NQ 200
#define FG 16
#define FL 64
#define FTOT 80
#define D 512
#define WAY 5
#define MROWS 2000    // 25*80 support rows
#define MPAD 2080     // padded to 13 tiles of 160
#define NROWS 16000   // 200*80 query rows

typedef unsigned char u8;
typedef __attribute__((ext_vector_type(4))) float floatx4;
typedef __attribute__((ext_vector_type(4))) int intx4;

__device__ inline void gload_lds16(const void* g, void* l) {
    __builtin_amdgcn_global_load_lds(
        (const __attribute__((address_space(1))) unsigned int*)g,
        (__attribute__((address_space(3))) unsigned int*)l, 16, 0, 0);
}

// One wave per 512-elem row: L2-normalize, cast fp8 e4m3 (OCP), write concat
// layout. Block 4500: zero Sn pad rows + zero out[] + per-class 1/count.
__global__ void normalize_kernel(const float* __restrict__ sg, const float* __restrict__ sl,
                                 const float* __restrict__ qg, const float* __restrict__ ql,
                                 u8* __restrict__ Sn, u8* __restrict__ Qn,
                                 const int* __restrict__ labels,
                                 float* __restrict__ out, float* __restrict__ rcnt) {
    if (blockIdx.x == 4500) {
        intx4 z = {0, 0, 0, 0};
        intx4* pad = (intx4*)(Sn + (size_t)MROWS * D);   // 80 rows * 512 B = 2560 intx4
        for (int i = threadIdx.x; i < (MPAD - MROWS) * D / 16; i += 256) pad[i] = z;
        for (int i = threadIdx.x; i < NQ * WAY; i += 256) out[i] = 0.f;
        if (threadIdx.x == 0) {
            int counts[WAY] = {0, 0, 0, 0, 0};
            for (int s = 0; s < NS; ++s) counts[labels[s]]++;
            for (int c = 0; c < WAY; ++c) rcnt[c] = 1.0f / (float)(counts[c] ? counts[c] : 1);
        }
        return;
    }
    int wave = (blockIdx.x * blockDim.x + threadIdx.x) >> 6;
    int lane = threadIdx.x & 63;
    const int totalRows = MROWS + NROWS;   // 18000
    if (wave >= totalRows) return;

    const float* src;
    u8* dst;
    if (wave < MROWS) {
        int s = wave / FTOT, f = wave % FTOT;
        src = (f < FG) ? sg + (size_t)(s * FG + f) * D
                       : sl + (size_t)(s * FL + (f - FG)) * D;
        dst = Sn + (size_t)wave * D;
    } else {
        int r = wave - MROWS;
        int q = r / FTOT, f = r % FTOT;
        src = (f < FG) ? qg + (size_t)(q * FG + f) * D
                       : ql + (size_t)(q * FL + (f - FG)) * D;
        dst = Qn + (size_t)r * D;
    }

    // lane holds 8 contiguous elements [8*lane .. 8*lane+8)
    float4 v0 = ((const float4*)src)[2 * lane];
    float4 v1 = ((const float4*)src)[2 * lane + 1];
    float ss = v0.x*v0.x + v0.y*v0.y + v0.z*v0.z + v0.w*v0.w
             + v1.x*v1.x + v1.y*v1.y + v1.z*v1.z + v1.w*v1.w;
    #pragma unroll
    for (int off = 32; off > 0; off >>= 1) ss += __shfl_xor(ss, off, 64);
    float scale = 1.0f / fmaxf(sqrtf(ss), 1e-12f);

    int w0 = __builtin_amdgcn_cvt_pk_fp8_f32(v0.x * scale, v0.y * scale, 0, false);
    w0     = __builtin_amdgcn_cvt_pk_fp8_f32(v0.z * scale, v0.w * scale, w0, true);
    int w1 = __builtin_amdgcn_cvt_pk_fp8_f32(v1.x * scale, v1.y * scale, 0, false);
    w1     = __builtin_amdgcn_cvt_pk_fp8_f32(v1.z * scale, v1.w * scale, w1, true);
    ((int2*)dst)[lane] = make_int2(w0, w1);
}

// 160x160-tile fp8 NT GEMM, BK=256 (2 K-chunks -> 2 barrier drains),
// 16-slot XOR-swizzled LDS. 4 waves 2x2; each wave owns one 80x80 (s,q)
// block = 5x5 MFMA 16x16x32 fp8 tiles. Epilogue fuses class-mean logits.
__global__ __launch_bounds__(256, 2) void gemm_kernel(const u8* __restrict__ Sn,
                                                      const u8* __restrict__ Qn,
                                                      const int* __restrict__ labels,
                                                      const float* __restrict__ rcnt,
                                                      float* __restrict__ out) {
    __shared__ u8 As[160][256];   // fp8, BK=256; 16B slot c holds global chunk c^(r&15)
    __shared__ u8 Bs[160][256];   // total 80 KB -> 2 blocks/CU (matches reg cap)

    const int bx = blockIdx.x;          // 0..99  (query groups, 2 per block)
    const int by = blockIdx.y;          // 0..12  (support groups, 2 per block)
    const int tid = threadIdx.x;
    const int lane = tid & 63;
    const int w = tid >> 6;
    const int lm = lane & 15;
    const int lq = lane >> 4;
    const int wr = w >> 1;              // which 80-row half
    const int wc = w & 1;               // which 80-col half

    floatx4 acc[5][5];
    #pragma unroll
    for (int i = 0; i < 5; ++i)
        #pragma unroll
        for (int j = 0; j < 5; ++j) acc[i][j] = (floatx4){0.f, 0.f, 0.f, 0.f};

    const u8* Sbase = Sn + (size_t)by * 160 * D;
    const u8* Qbase = Qn + (size_t)bx * 160 * D;

    // staging: waves 0,1 -> A; waves 2,3 -> B. 40 slabs of 4 rows (1 KB each).
    const u8* gsrc = (w < 2) ? Sbase : Qbase;
    u8* ldst = (w < 2) ? (u8*)As : (u8*)Bs;
    const int sl0 = (w & 1) * 20;
    const int grow = lane >> 4;         // row 0..3 within slab
    const int gc = lane & 15;           // 16B slot within 256B row

    #pragma unroll 1
    for (int kc = 0; kc < 2; ++kc) {
        const int k0 = kc * 256;
        __syncthreads();                // prev chunk's readers done
        #pragma unroll
        for (int t = 0; t < 20; ++t) {
            const int sl = sl0 + t;
            const int r = sl * 4 + grow;
            const int cp = gc ^ (r & 15);
            gload_lds16(gsrc + (size_t)r * D + k0 + cp * 16, ldst + sl * 1024);
        }
        __syncthreads();                // drains vmcnt (global_load_lds) too
        #pragma unroll
        for (int ks = 0; ks < 8; ++ks) {
            long long a[5], b[5];
            #pragma unroll
            for (int i = 0; i < 5; ++i) {
                const int r = wr * 80 + i * 16 + lm;
                const int c = (ks * 2 + (lq >> 1)) ^ (r & 15);
                a[i] = *(const long long*)(&As[r][c * 16 + (lq & 1) * 8]);
            }
            #pragma unroll
            for (int j = 0; j < 5; ++j) {
                const int r = wc * 80 + j * 16 + lm;
                const int c = (ks * 2 + (lq >> 1)) ^ (r & 15);
                b[j] = *(const long long*)(&Bs[r][c * 16 + (lq & 1) * 8]);
            }
            #pragma unroll
            for (int i = 0; i < 5; ++i)
                #pragma unroll
                for (int j = 0; j < 5; ++j)
                    acc[i][j] = __builtin_amdgcn_mfma_f32_16x16x32_fp8_fp8(a[i], b[j], acc[i][j], 0, 0, 0);
        }
    }

    // Epilogue: sum (1-sim)^2 over the wave's 80x80 block, fuse class-mean.
    float local = 0.f;
    #pragma unroll
    for (int i = 0; i < 5; ++i)
        #pragma unroll
        for (int j = 0; j < 5; ++j)
            #pragma unroll
            for (int r = 0; r < 4; ++r) {
                const float d = 1.0f - acc[i][j][r];
                local = fmaf(d, d, local);
            }
    #pragma unroll
    for (int off = 32; off > 0; off >>= 1) local += __shfl_down(local, off, 64);

    const int sIdx = by * 2 + wr;       // 25 = pad group, dropped
    const int qIdx = bx * 2 + wc;
    if (lane == 0 && sIdx < NS) {
        const int c = labels[sIdx];
        atomicAdd(&out[qIdx * WAY + c], -2.0f * local * rcnt[c]);
    }
}

extern "C" void kernel_launch(void* const* d_in, const int* in_sizes, int n_in,
                              void* d_out, int out_size, void* d_ws, size_t ws_size,
                              hipStream_t stream) {
    const float* sg = (const float*)d_in[0];
    const float* sl = (const float*)d_in[1];
    const int* labels = (const int*)d_in[2];
    const float* qg = (const float*)d_in[3];
    const float* ql = (const float*)d_in[4];
    float* out = (float*)d_out;

    u8* Sn = (u8*)d_ws;                          // 2080*512 fp8 (padded)
    u8* Qn = Sn + (size_t)MPAD * D;              // 16000*512 fp8
    float* rcnt = (float*)(Qn + (size_t)NROWS * D);

    normalize_kernel<<<4501, 256, 0, stream>>>(sg, sl, qg, ql, Sn, Qn, labels, out, rcnt);
    dim3 g2(100, 13);
    gemm_kernel<<<g2, 256, 0, stream>>>(Sn, Qn, labels, rcnt, out);
}

// Round 7
// 109.516 us; speedup vs baseline: 1.1381x; 1.0619x over previous
//
#include <hip/hip_runtime.h>

#define NS 25
#define NQ 200
#define FG 16
#define FL 64
#define FTOT 80
#define D 512
#define WAY 5
#define MROWS 2000    // 25*80 support rows
#define MPAD 2080     // padded to 13 tiles of 160
#define NROWS 16000   // 200*80 query rows

typedef unsigned char u8;
typedef __attribute__((ext_vector_type(4))) float floatx4;
typedef __attribute__((ext_vector_type(4))) int intx4;

__device__ inline void gload_lds16(const void* g, void* l) {
    __builtin_amdgcn_global_load_lds(
        (const __attribute__((address_space(1))) unsigned int*)g,
        (__attribute__((address_space(3))) unsigned int*)l, 16, 0, 0);
}

// One wave per 512-elem row: L2-normalize, cast fp8 e4m3 (OCP), write concat
// layout. Block 4500: zero Sn pad rows + zero out[] + per-class 1/count.
__global__ void normalize_kernel(const float* __restrict__ sg, const float* __restrict__ sl,
                                 const float* __restrict__ qg, const float* __restrict__ ql,
                                 u8* __restrict__ Sn, u8* __restrict__ Qn,
                                 const int* __restrict__ labels,
                                 float* __restrict__ out, float* __restrict__ rcnt) {
    if (blockIdx.x == 4500) {
        intx4 z = {0, 0, 0, 0};
        intx4* pad = (intx4*)(Sn + (size_t)MROWS * D);   // 80 rows * 512 B = 2560 intx4
        for (int i = threadIdx.x; i < (MPAD - MROWS) * D / 16; i += 256) pad[i] = z;
        for (int i = threadIdx.x; i < NQ * WAY; i += 256) out[i] = 0.f;
        if (threadIdx.x == 0) {
            int counts[WAY] = {0, 0, 0, 0, 0};
            for (int s = 0; s < NS; ++s) counts[labels[s]]++;
            for (int c = 0; c < WAY; ++c) rcnt[c] = 1.0f / (float)(counts[c] ? counts[c] : 1);
        }
        return;
    }
    int wave = (blockIdx.x * blockDim.x + threadIdx.x) >> 6;
    int lane = threadIdx.x & 63;
    const int totalRows = MROWS + NROWS;   // 18000
    if (wave >= totalRows) return;

    const float* src;
    u8* dst;
    if (wave < MROWS) {
        int s = wave / FTOT, f = wave % FTOT;
        src = (f < FG) ? sg + (size_t)(s * FG + f) * D
                       : sl + (size_t)(s * FL + (f - FG)) * D;
        dst = Sn + (size_t)wave * D;
    } else {
        int r = wave - MROWS;
        int q = r / FTOT, f = r % FTOT;
        src = (f < FG) ? qg + (size_t)(q * FG + f) * D
                       : ql + (size_t)(q * FL + (f - FG)) * D;
        dst = Qn + (size_t)r * D;
    }

    // lane holds 8 contiguous elements [8*lane .. 8*lane+8)
    float4 v0 = ((const float4*)src)[2 * lane];
    float4 v1 = ((const float4*)src)[2 * lane + 1];
    float ss = v0.x*v0.x + v0.y*v0.y + v0.z*v0.z + v0.w*v0.w
             + v1.x*v1.x + v1.y*v1.y + v1.z*v1.z + v1.w*v1.w;
    #pragma unroll
    for (int off = 32; off > 0; off >>= 1) ss += __shfl_xor(ss, off, 64);
    float scale = 1.0f / fmaxf(sqrtf(ss), 1e-12f);

    int w0 = __builtin_amdgcn_cvt_pk_fp8_f32(v0.x * scale, v0.y * scale, 0, false);
    w0     = __builtin_amdgcn_cvt_pk_fp8_f32(v0.z * scale, v0.w * scale, w0, true);
    int w1 = __builtin_amdgcn_cvt_pk_fp8_f32(v1.x * scale, v1.y * scale, 0, false);
    w1     = __builtin_amdgcn_cvt_pk_fp8_f32(v1.z * scale, v1.w * scale, w1, true);
    ((int2*)dst)[lane] = make_int2(w0, w1);
}

// 160x160-tile fp8 NT GEMM, BK=128, XOR-swizzled LDS (8 slots, ^((r>>1)&7)).
// 4 waves 2x2; each wave owns one 80x80 (s,q) block = 5x5 MFMA 16x16x32 fp8
// tiles. Epilogue: sum (1-sim)^2 -> fused class-mean logits, 1 atomic/wave.
// launch_bounds (256,2): true occupancy is 2 waves/SIMD (acc=100 + ~84 arch
// regs = ~184); declaring 3 caps the allocator at 170 and forces remat/spill.
__global__ __launch_bounds__(256, 2) void gemm_kernel(const u8* __restrict__ Sn,
                                                      const u8* __restrict__ Qn,
                                                      const int* __restrict__ labels,
                                                      const float* __restrict__ rcnt,
                                                      float* __restrict__ out) {
    __shared__ u8 As[160][128];   // fp8, BK=128; 16B slot c holds global chunk c^((r>>1)&7)
    __shared__ u8 Bs[160][128];   // 40 KB total -> LDS not the occupancy cap

    const int bx = blockIdx.x;          // 0..99  (query groups, 2 per block)
    const int by = blockIdx.y;          // 0..12  (support groups, 2 per block)
    const int tid = threadIdx.x;
    const int lane = tid & 63;
    const int w = tid >> 6;
    const int lm = lane & 15;
    const int lq = lane >> 4;
    const int wr = w >> 1;              // which 80-row half
    const int wc = w & 1;               // which 80-col half

    floatx4 acc[5][5];
    #pragma unroll
    for (int i = 0; i < 5; ++i)
        #pragma unroll
        for (int j = 0; j < 5; ++j) acc[i][j] = (floatx4){0.f, 0.f, 0.f, 0.f};

    const u8* Sbase = Sn + (size_t)by * 160 * D;
    const u8* Qbase = Qn + (size_t)bx * 160 * D;

    // staging: waves 0,1 -> A; waves 2,3 -> B. 20 slabs of 8 rows (1 KB each).
    const u8* gsrc = (w < 2) ? Sbase : Qbase;
    u8* ldst = (w < 2) ? (u8*)As : (u8*)Bs;
    const int sl0 = (w & 1) * 10;
    const int grow = lane >> 3;         // row within 8-row slab
    const int gc = lane & 7;            // 16B slot within 128B row

    #pragma unroll 1
    for (int kc = 0; kc < 4; ++kc) {
        const int k0 = kc * 128;
        __syncthreads();                // prev chunk's readers done
        #pragma unroll
        for (int t = 0; t < 10; ++t) {
            const int sl = sl0 + t;
            const int r = sl * 8 + grow;
            const int cp = gc ^ ((r >> 1) & 7);
            gload_lds16(gsrc + (size_t)r * D + k0 + cp * 16, ldst + sl * 1024);
        }
        __syncthreads();                // drains vmcnt (global_load_lds) too
        #pragma unroll
        for (int ks = 0; ks < 4; ++ks) {
            long long a[5], b[5];
            #pragma unroll
            for (int i = 0; i < 5; ++i) {
                const int r = wr * 80 + i * 16 + lm;
                const int c = (ks * 2 + (lq >> 1)) ^ ((r >> 1) & 7);
                a[i] = *(const long long*)(&As[r][c * 16 + (lq & 1) * 8]);
            }
            #pragma unroll
            for (int j = 0; j < 5; ++j) {
                const int r = wc * 80 + j * 16 + lm;
                const int c = (ks * 2 + (lq >> 1)) ^ ((r >> 1) & 7);
                b[j] = *(const long long*)(&Bs[r][c * 16 + (lq & 1) * 8]);
            }
            #pragma unroll
            for (int i = 0; i < 5; ++i)
                #pragma unroll
                for (int j = 0; j < 5; ++j)
                    acc[i][j] = __builtin_amdgcn_mfma_f32_16x16x32_fp8_fp8(a[i], b[j], acc[i][j], 0, 0, 0);
        }
    }

    // Epilogue: sum (1-sim)^2 over the wave's 80x80 block, fuse class-mean.
    float local = 0.f;
    #pragma unroll
    for (int i = 0; i < 5; ++i)
        #pragma unroll
        for (int j = 0; j < 5; ++j)
            #pragma unroll
            for (int r = 0; r < 4; ++r) {
                const float d = 1.0f - acc[i][j][r];
                local = fmaf(d, d, local);
            }
    #pragma unroll
    for (int off = 32; off > 0; off >>= 1) local += __shfl_down(local, off, 64);

    const int sIdx = by * 2 + wr;       // 25 = pad group, dropped
    const int qIdx = bx * 2 + wc;
    if (lane == 0 && sIdx < NS) {
        const int c = labels[sIdx];
        atomicAdd(&out[qIdx * WAY + c], -2.0f * local * rcnt[c]);
    }
}

extern "C" void kernel_launch(void* const* d_in, const int* in_sizes, int n_in,
                              void* d_out, int out_size, void* d_ws, size_t ws_size,
                              hipStream_t stream) {
    const float* sg = (const float*)d_in[0];
    const float* sl = (const float*)d_in[1];
    const int* labels = (const int*)d_in[2];
    const float* qg = (const float*)d_in[3];
    const float* ql = (const float*)d_in[4];
    float* out = (float*)d_out;

    u8* Sn = (u8*)d_ws;                          // 2080*512 fp8 (padded)
    u8* Qn = Sn + (size_t)MPAD * D;              // 16000*512 fp8
    float* rcnt = (float*)(Qn + (size_t)NROWS * D);

    normalize_kernel<<<4501, 256, 0, stream>>>(sg, sl, qg, ql, Sn, Qn, labels, out, rcnt);
    dim3 g2(100, 13);
    gemm_kernel<<<g2, 256, 0, stream>>>(Sn, Qn, labels, rcnt, out);
}